// Round 9
// baseline (79.788 us; speedup 1.0000x reference)
//
#include <hip/hip_runtime.h>

#define NS 65536

typedef float f32x4 __attribute__((ext_vector_type(4)));
typedef float f32x2 __attribute__((ext_vector_type(2)));

// out[b][n] = sin(2*pi*phi) * fm * window * sin(pi*am*t)
//   phi    = 440/(fm*ln2) * (exp2(fm*t) - 1),  t = (n - 32768)/44100
//   wsupp  = n - 32767.5;  window = 2^(-k2*wsupp^2)
//   am_hz = exp2(2*theta_am+2), fm_hz = exp2(3*theta_fm-1)
//
// R9 = compute-ablation round (is the kernel compute-bound or store-bound?):
//  1) per-batch constants computed by lane 0 only -> LDS (preamble trans
//     15 -> 4 per thread; they were block-uniform all along)
//  2) even/odd packed chains in the inner loop: samples {0,2} and {1,3}
//     step by r2=r1^2; window 2-step ratio v2=v1^2*P1 (ratio-of-ratios
//     P1^4 absorbed by re-anchoring per group); modulator via one +1
//     rotation + one packed +2 rotation. ~55 -> ~38 VALU/group.
// Layout/balance/stores identical to R8 (strided groups, plain f32x4 stores).
__global__ __launch_bounds__(256) void chirplet_synth_kernel(
    const float* __restrict__ theta_am,
    const float* __restrict__ theta_fm,
    float* __restrict__ out)
{
    enum { C_FM, C_CPH, C_R1, C_R2, C_RG, C_K2, C_P1, C_P1SQ, C_PG,
           C_AMT, C_SD1, C_CD1, C_SD2, C_CD2, C_SDG, C_CDG, C_N };
    __shared__ float cst[C_N];

    const int bid  = blockIdx.x;
    const int b    = bid >> 3;                 // batch (block-uniform)
    const int c    = bid & 7;                  // group phase 0..7
    const int tid4 = threadIdx.x << 2;

    if (threadIdx.x == 0) {
        const float inv_sr = 1.0f / 44100.0f;
        const float fm  = exp2f(theta_fm[b] * 3.0f - 1.0f);
        const float am  = exp2f(theta_am[b] * 2.0f + 2.0f);
        const float r1  = exp2f(fm * inv_sr);
        const float invd = fm * (1.0f / 6236.68503f);
        const float k2  = invd * invd * 1.44269504f;
        const float P1  = exp2f(-2.0f * k2);
        const float m1  = am * (0.5f * inv_sr);
        cst[C_FM]  = fm;
        cst[C_CPH] = 440.0f / (fm * 0.69314718055994531f);
        cst[C_R1]  = r1;
        cst[C_R2]  = r1 * r1;
        cst[C_RG]  = exp2f(fm * (8192.0f * inv_sr));
        cst[C_K2]  = k2;
        cst[C_P1]  = P1;
        cst[C_P1SQ]= P1 * P1;
        cst[C_PG]  = exp2f(-16384.0f * k2);
        cst[C_AMT] = am * 0.5f;
        cst[C_SD1] = __builtin_amdgcn_sinf(m1);
        cst[C_CD1] = __builtin_amdgcn_cosf(m1);
        cst[C_SD2] = __builtin_amdgcn_sinf(2.0f * m1);
        cst[C_CD2] = __builtin_amdgcn_cosf(2.0f * m1);
        const float mG = __builtin_amdgcn_fractf(m1 * 8192.0f);
        cst[C_SDG] = __builtin_amdgcn_sinf(mG);
        cst[C_CDG] = __builtin_amdgcn_cosf(mG);
    }
    __syncthreads();

    const float fm  = cst[C_FM],  cph  = cst[C_CPH];
    const float r1  = cst[C_R1],  r2   = cst[C_R2],  rG = cst[C_RG];
    const float k2  = cst[C_K2],  P1   = cst[C_P1],  P1sq = cst[C_P1SQ], PG = cst[C_PG];
    const float amt = cst[C_AMT];
    const float sd1 = cst[C_SD1], cd1  = cst[C_CD1];
    const float sd2 = cst[C_SD2], cd2  = cst[C_CD2];
    const float sdG = cst[C_SDG], cdG  = cst[C_CDG];

    // per-thread anchors at first group (gi = 0): 4 trans total
    const int   n0  = (c << 10) + tid4;
    const float nf0 = (float)n0;
    const float inv_sr = 1.0f / 44100.0f;
    const float t0  = (nf0 - 32768.0f) * inv_sr;
    const float ws0 = nf0 - 32767.5f;

    float e  = exp2f(fm * t0);                       // 2^(fm*t), safe range
    float vv = exp2f(-k2 * (2.0f * ws0 + 1.0f));     // v1 at group start (~1.0)
    const float th0 = __builtin_amdgcn_fractf(amt * t0);
    float s  = __builtin_amdgcn_sinf(th0);
    float cn = __builtin_amdgcn_cosf(th0);

    float* outp = out + (size_t)b * NS + n0;
    const f32x4 z = {0.f, 0.f, 0.f, 0.f};

#pragma unroll
    for (int gi = 0; gi < 8; ++gi) {
        const float ws = ws0 + (float)(gi << 13);
        const float q  = -k2 * ws * ws;              // log2(window)
        float* o = outp + (gi << 13);

        if (q > -36.5f) {                            // group alive
            // window: even/odd anchors + one packed 2-step
            const float g0  = fm * exp2f(q);         // fresh anchor (R5 lesson)
            const float v1  = vv;
            const float v20 = v1 * v1 * P1;          // w(n+2)/w(n) at even
            const float v21 = v20 * P1sq;            // at odd
            const f32x2 g01 = {g0, g0 * v1};
            const f32x2 v2  = {v20, v21};
            const f32x2 g23 = g01 * v2;

            // carrier exponent: even/odd packed chains
            const f32x2 le01 = {e, e * r1};
            const f32x2 le23 = le01 * r2;
            const f32x2 phi01 = le01 * cph - cph;    // cph*(e-1)
            const f32x2 phi23 = le23 * cph - cph;
            const float carr0 = __builtin_amdgcn_sinf(__builtin_amdgcn_fractf(phi01.x));
            const float carr1 = __builtin_amdgcn_sinf(__builtin_amdgcn_fractf(phi01.y));
            const float carr2 = __builtin_amdgcn_sinf(__builtin_amdgcn_fractf(phi23.x));
            const float carr3 = __builtin_amdgcn_sinf(__builtin_amdgcn_fractf(phi23.y));

            // modulator: +1 rotation then packed +2 rotation (sin only needed)
            const float s1 = __builtin_fmaf(s,  cd1,  cn * sd1);
            const float c1 = __builtin_fmaf(cn, cd1, -s  * sd1);
            const f32x2 s01 = {s, s1};
            const f32x2 c01 = {cn, c1};
            const f32x2 s23 = s01 * cd2 + c01 * sd2;

            const f32x2 gs01 = g01 * s01;
            const f32x2 gs23 = g23 * s23;
            const f32x4 r = {carr0 * gs01.x, carr1 * gs01.y,
                             carr2 * gs23.x, carr3 * gs23.y};
            *reinterpret_cast<f32x4*>(o) = r;
        } else {                                     // group dead -> zeros
            *reinterpret_cast<f32x4*>(o) = z;
        }

        // advance chains by +8192 samples (uniform, alive or dead)
        e  *= rG;
        vv *= PG;
        const float ns2 = __builtin_fmaf(s,  cdG,  cn * sdG);
        const float nc2 = __builtin_fmaf(cn, cdG, -s  * sdG);
        s = ns2; cn = nc2;
    }
}

extern "C" void kernel_launch(void* const* d_in, const int* in_sizes, int n_in,
                              void* d_out, int out_size, void* d_ws, size_t ws_size,
                              hipStream_t stream) {
    const float* theta_am = (const float*)d_in[0];
    const float* theta_fm = (const float*)d_in[1];
    // d_in[2] (seed) is unused by the reference
    float* out = (float*)d_out;

    const int B = in_sizes[0];                       // 256
    dim3 grid(B << 3), block(256);                   // 2048 blocks
    chirplet_synth_kernel<<<grid, block, 0, stream>>>(theta_am, theta_fm, out);
}